// Round 2
// baseline (3161.172 us; speedup 1.0000x reference)
//
#include <hip/hip_runtime.h>
#include <hip/hip_fp16.h>

typedef _Float16 f16;
typedef _Float16 f16x8 __attribute__((ext_vector_type(8)));
typedef _Float16 f16x4 __attribute__((ext_vector_type(4)));
typedef float    f32x4 __attribute__((ext_vector_type(4)));

__device__ __forceinline__ f32x4 mfma16(f16x8 a, f16x8 b, f32x4 c){
  return __builtin_amdgcn_mfma_f32_16x16x32_f16(a, b, c, 0, 0, 0);
}
__device__ __forceinline__ int imin(int a, int b){ return a < b ? a : b; }

// ---------------------------------------------------------------- f32 -> f16
__global__ void cvt_kernel(const float* __restrict__ src, f16* __restrict__ dst, int n4){
  int i = blockIdx.x * 256 + threadIdx.x;
  if (i < n4){
    float4 v = reinterpret_cast<const float4*>(src)[i];
    f16x4 h;
    h[0] = (f16)v.x; h[1] = (f16)v.y; h[2] = (f16)v.z; h[3] = (f16)v.w;
    reinterpret_cast<f16x4*>(dst)[i] = h;
  }
}

// ---------------------------------------------------------------- rel kernel
// grid: 2048 blocks = (bq in [0,128)) x (g in [0,16)), 256 threads (4 waves).
__global__ __launch_bounds__(256) void krel(
    const f16* __restrict__ xh, const f16* __restrict__ Wth, const f16* __restrict__ Wph,
    const float* __restrict__ bth, const float* __restrict__ bph,
    const float* __restrict__ boxes, float* __restrict__ relw, float* __restrict__ out2)
{
  const int bid  = blockIdx.x;
  const int slot = bid & 7, idx = bid >> 3;          // XCD swizzle: same g stays on one XCD
  const int g    = slot + ((idx >> 7) << 3);
  const int bq   = idx & 127;
  const int tid  = threadIdx.x;
  const int w    = tid >> 6, lane = tid & 63;
  const int l15  = lane & 15, l4 = lane >> 4;

  __shared__ f16 thS[48][264];
  __shared__ f16 phS[48][264];

  const f32x4 fz = {0.f, 0.f, 0.f, 0.f};
  f32x4 accT[3][4], accP[3][4];
  #pragma unroll
  for (int mt = 0; mt < 3; ++mt)
    #pragma unroll
    for (int j = 0; j < 4; ++j){ accT[mt][j] = fz; accP[mt][j] = fz; }

  const f16* Ab = xh  + (size_t)(bq*48 + l15)*1024 + l4*8;
  const f16* Tb = Wth + (size_t)(g*256 + w*64 + l15)*1024 + l4*8;
  const f16* Pb = Wph + (size_t)(g*256 + w*64 + l15)*1024 + l4*8;

  for (int kk = 0; kk < 32; ++kk){
    const int f = kk << 5;
    f16x8 a[3], bt[4], bp[4];
    #pragma unroll
    for (int mt = 0; mt < 3; ++mt) a[mt] = *(const f16x8*)(Ab + mt*16*1024 + f);
    #pragma unroll
    for (int j = 0; j < 4; ++j){
      bt[j] = *(const f16x8*)(Tb + j*16*1024 + f);
      bp[j] = *(const f16x8*)(Pb + j*16*1024 + f);
    }
    #pragma unroll
    for (int mt = 0; mt < 3; ++mt)
      #pragma unroll
      for (int j = 0; j < 4; ++j){
        accT[mt][j] = mfma16(a[mt], bt[j], accT[mt][j]);
        accP[mt][j] = mfma16(a[mt], bp[j], accP[mt][j]);
      }
  }

  #pragma unroll
  for (int j = 0; j < 4; ++j){
    const int ko = w*64 + j*16 + l15;
    const float bT = bth[g*256 + ko];
    const float bP = bph[g*256 + ko];
    #pragma unroll
    for (int mt = 0; mt < 3; ++mt)
      #pragma unroll
      for (int r = 0; r < 4; ++r){
        const int row = mt*16 + l4*4 + r;
        thS[row][ko] = (f16)(accT[mt][j][r] + bT);
        phS[row][ko] = (f16)(accP[mt][j][r] + bP);
      }
  }
  __syncthreads();

  const int bi = w;
  const int bglob = bq*4 + bi;
  f32x4 sa = fz;
  const int arow = imin(bi*12 + l15, 47);
  #pragma unroll
  for (int k8 = 0; k8 < 8; ++k8){
    const f16x8 a = *(const f16x8*)(&thS[arow][k8*32 + l4*8]);
    const f16x8 b = *(const f16x8*)(&phS[arow][k8*32 + l4*8]);
    sa = mfma16(a, b, sa);
  }
  const int m  = l15;
  const int mc = imin(m, 11);
  const float4 bxm = *(const float4*)(boxes + (size_t)(bglob*12 + mc)*4);
  const float cxm = (bxm.x + bxm.z)*0.5f, cym = (bxm.y + bxm.w)*0.5f;
  const float sqm = cxm*cxm + cym*cym;
  #pragma unroll
  for (int r = 0; r < 4; ++r){
    const int n  = l4*4 + r;
    const int nc = imin(n, 11);
    const float4 bxn = *(const float4*)(boxes + (size_t)(bglob*12 + nc)*4);
    const float cxn = (bxn.x + bxn.z)*0.5f, cyn = (bxn.y + bxn.w)*0.5f;
    const float sqn = cxn*cxn + cyn*cyn;
    const float dot = cxn*cxm + cyn*cym;
    const float d2  = (sqn - 2.f*dot) + sqm;
    const float dist = sqrtf(fmaxf(d2, 0.f));
    float val = sa[r] * 0.0625f;
    if (dist > 0.2f || m >= 12) val = -__builtin_inff();
    float mx = val;
    #pragma unroll
    for (int d = 1; d < 16; d <<= 1) mx = fmaxf(mx, __shfl_xor(mx, d));
    const float e = expf(val - mx);
    float s = e;
    #pragma unroll
    for (int d = 1; d < 16; d <<= 1) s += __shfl_xor(s, d);
    const float rv = e / s;
    if (n < 12 && m < 12){
      relw[((size_t)(bglob*16 + g))*144 + n*12 + m] = rv;
      if (g == 15) out2[(size_t)bglob*144 + n*12 + m] = rv;
    }
  }
}

// ---------------------------------------------------------------- h kernel
// grid: 2048 blocks = (bq,g), 512 threads (8 waves).
// WS=true : write post-LN/relu rows as f16 to hnw (no atomics), reduced later.
// WS=false: legacy atomicAdd path (fallback if workspace too small).
template<bool WS>
__global__ __launch_bounds__(512) void kh(
    const f16* __restrict__ xh, const f16* __restrict__ Wgh,
    const float* __restrict__ relw, const float* __restrict__ gam,
    const float* __restrict__ bet, float* __restrict__ out1, f16* __restrict__ hnw)
{
  const int bid  = blockIdx.x;
  const int slot = bid & 7, idx = bid >> 3;
  const int g    = slot + ((idx >> 7) << 3);
  const int bq   = idx & 127;
  const int tid  = threadIdx.x;
  const int w    = tid >> 6, lane = tid & 63;
  const int l15  = lane & 15, l4 = lane >> 4;

  __shared__ f16   ylds[48][520];
  __shared__ float rel_s[4][144];
  __shared__ float stats[48][2];

  for (int t = tid; t < 576; t += 512){
    int bi = t / 144, nm = t % 144;
    rel_s[bi][nm] = relw[((size_t)((bq*4 + bi)*16 + g))*144 + nm];
  }

  const f32x4 fz = {0.f, 0.f, 0.f, 0.f};
  f32x4 acc[3][8];
  #pragma unroll
  for (int mt = 0; mt < 3; ++mt)
    #pragma unroll
    for (int j = 0; j < 8; ++j) acc[mt][j] = fz;

  const f16* Ab = xh  + (size_t)(bq*48 + l15)*1024 + l4*8;
  const f16* Bb = Wgh + (size_t)(g*1024 + w*128 + l15)*1024 + l4*8;

  for (int kk = 0; kk < 32; ++kk){
    const int f = kk << 5;
    f16x8 a[3], b[8];
    #pragma unroll
    for (int mt = 0; mt < 3; ++mt) a[mt] = *(const f16x8*)(Ab + mt*16*1024 + f);
    #pragma unroll
    for (int j = 0; j < 8; ++j)   b[j]  = *(const f16x8*)(Bb + j*16*1024 + f);
    #pragma unroll
    for (int mt = 0; mt < 3; ++mt)
      #pragma unroll
      for (int j = 0; j < 8; ++j)
        acc[mt][j] = mfma16(a[mt], b[j], acc[mt][j]);
  }
  __syncthreads();

  float srow[6], s2row[6];
  #pragma unroll
  for (int i = 0; i < 6; ++i){ srow[i] = 0.f; s2row[i] = 0.f; }

  #pragma unroll
  for (int half = 0; half < 2; ++half){
    if ((w >> 2) == half){
      const int ww = w & 3;
      #pragma unroll
      for (int mt = 0; mt < 3; ++mt)
        #pragma unroll
        for (int j = 0; j < 8; ++j){
          const int o = ww*128 + j*16 + l15;
          #pragma unroll
          for (int r = 0; r < 4; ++r)
            ylds[mt*16 + l4*4 + r][o] = (f16)acc[mt][j][r];
        }
    }
    __syncthreads();
    #pragma unroll
    for (int i = 0; i < 6; ++i){
      const int row = w*6 + i;
      const int bi = row / 12, n = row % 12;
      const float* rl = &rel_s[bi][n*12];
      float h[8];
      #pragma unroll
      for (int t = 0; t < 8; ++t) h[t] = 0.f;
      #pragma unroll
      for (int mm = 0; mm < 12; ++mm){
        const f16x8 yv = *(const f16x8*)(&ylds[bi*12 + mm][lane*8]);
        const float rv = rl[mm];
        #pragma unroll
        for (int t = 0; t < 8; ++t) h[t] = fmaf(rv, (float)yv[t], h[t]);
      }
      float ls = 0.f, l2 = 0.f;
      #pragma unroll
      for (int t = 0; t < 8; ++t){ ls += h[t]; l2 = fmaf(h[t], h[t], l2); }
      srow[i] += ls; s2row[i] += l2;
    }
    __syncthreads();
  }

  #pragma unroll
  for (int i = 0; i < 6; ++i){
    float s = srow[i], s2 = s2row[i];
    #pragma unroll
    for (int d = 1; d < 64; d <<= 1){
      s  += __shfl_xor(s, d);
      s2 += __shfl_xor(s2, d);
    }
    if (lane == 0){ stats[w*6 + i][0] = s; stats[w*6 + i][1] = s2; }
  }
  __syncthreads();

  #pragma unroll
  for (int pass = 0; pass < 2; ++pass){
    const int half = 1 - pass;
    if (pass == 1){
      if (w < 4){
        #pragma unroll
        for (int mt = 0; mt < 3; ++mt)
          #pragma unroll
          for (int j = 0; j < 8; ++j){
            const int o = w*128 + j*16 + l15;
            #pragma unroll
            for (int r = 0; r < 4; ++r)
              ylds[mt*16 + l4*4 + r][o] = (f16)acc[mt][j][r];
          }
      }
      __syncthreads();
    }
    const int obase = half*512 + lane*8;
    const float4 ga0 = *(const float4*)(gam + (size_t)g*1024 + obase);
    const float4 ga1 = *(const float4*)(gam + (size_t)g*1024 + obase + 4);
    const float4 be0 = *(const float4*)(bet + (size_t)g*1024 + obase);
    const float4 be1 = *(const float4*)(bet + (size_t)g*1024 + obase + 4);
    const float gv[8] = {ga0.x,ga0.y,ga0.z,ga0.w,ga1.x,ga1.y,ga1.z,ga1.w};
    const float bv[8] = {be0.x,be0.y,be0.z,be0.w,be1.x,be1.y,be1.z,be1.w};
    #pragma unroll
    for (int i = 0; i < 6; ++i){
      const int row = w*6 + i;
      const int bi = row / 12, n = row % 12;
      const float* rl = &rel_s[bi][n*12];
      float h[8];
      #pragma unroll
      for (int t = 0; t < 8; ++t) h[t] = 0.f;
      #pragma unroll
      for (int mm = 0; mm < 12; ++mm){
        const f16x8 yv = *(const f16x8*)(&ylds[bi*12 + mm][lane*8]);
        const float rv = rl[mm];
        #pragma unroll
        for (int t = 0; t < 8; ++t) h[t] = fmaf(rv, (float)yv[t], h[t]);
      }
      const float mu  = stats[row][0] * (1.f/1024.f);
      const float var = stats[row][1] * (1.f/1024.f) - mu*mu;
      const float rs  = rsqrtf(var + 1e-5f);
      if (WS){
        f16x8 hv;
        #pragma unroll
        for (int t = 0; t < 8; ++t){
          float v = (h[t] - mu)*rs*gv[t] + bv[t];
          hv[t] = (f16)fmaxf(v, 0.f);
        }
        *(f16x8*)(hnw + ((size_t)g*6144 + bq*48 + row)*1024 + obase) = hv;
      } else {
        float* op = out1 + (size_t)(bq*48 + row)*1024 + obase;
        #pragma unroll
        for (int t = 0; t < 8; ++t){
          float v = (h[t] - mu)*rs*gv[t] + bv[t];
          v = fmaxf(v, 0.f);
          atomicAdd(op + t, v);
        }
      }
    }
    if (pass == 0) __syncthreads();
  }
}

// ---------------------------------------------------------------- reduce over g
// out1[i] = sum_g hnw[g][i]; i over 6.29M floats, 8 per thread.
__global__ __launch_bounds__(256) void kreduce(const f16* __restrict__ hnw,
                                               float* __restrict__ out1, int n8){
  int i = blockIdx.x * 256 + threadIdx.x;
  if (i >= n8) return;
  float acc[8];
  #pragma unroll
  for (int t = 0; t < 8; ++t) acc[t] = 0.f;
  #pragma unroll
  for (int g = 0; g < 16; ++g){
    const f16x8 v = reinterpret_cast<const f16x8*>(hnw + (size_t)g*6291456)[i];
    #pragma unroll
    for (int t = 0; t < 8; ++t) acc[t] += (float)v[t];
  }
  float4 o0 = {acc[0], acc[1], acc[2], acc[3]};
  float4 o1 = {acc[4], acc[5], acc[6], acc[7]};
  reinterpret_cast<float4*>(out1)[i*2]     = o0;
  reinterpret_cast<float4*>(out1)[i*2 + 1] = o1;
}

// ---------------------------------------------------------------- launcher
extern "C" void kernel_launch(void* const* d_in, const int* in_sizes, int n_in,
                              void* d_out, int out_size, void* d_ws, size_t ws_size,
                              hipStream_t stream)
{
  const float* x_f   = (const float*)d_in[0];
  const float* boxes = (const float*)d_in[1];
  const float* Wt_f  = (const float*)d_in[2];
  const float* bt_f  = (const float*)d_in[3];
  const float* Wp_f  = (const float*)d_in[4];
  const float* bp_f  = (const float*)d_in[5];
  const float* Wg_f  = (const float*)d_in[6];
  const float* gam   = (const float*)d_in[7];
  const float* bet   = (const float*)d_in[8];

  float* out1 = (float*)d_out;
  float* out2 = out1 + (size_t)512*12*1024;

  char* ws = (char*)d_ws;
  f16*  xh   = (f16*)(ws);                      // 12,582,912 B
  f16*  Wth  = (f16*)(ws + 12582912);           //  8,388,608 B
  f16*  Wph  = (f16*)(ws + 20971520);           //  8,388,608 B
  f16*  Wgh  = (f16*)(ws + 29360128);           // 33,554,432 B
  float* relw = (float*)(ws + 62914560);        //  4,718,592 B
  f16*  hnw  = (f16*)(ws + 67633152);           // 201,326,592 B (WS path only)
  const size_t need = 67633152u + 201326592u;   // ~256.5 MiB

  const bool use_ws = (ws_size >= need);

  cvt_kernel<<<6144,  256, 0, stream>>>(x_f,  xh,  6291456/4);
  cvt_kernel<<<4096,  256, 0, stream>>>(Wt_f, Wth, 4194304/4);
  cvt_kernel<<<4096,  256, 0, stream>>>(Wp_f, Wph, 4194304/4);
  cvt_kernel<<<16384, 256, 0, stream>>>(Wg_f, Wgh, 16777216/4);

  krel<<<2048, 256, 0, stream>>>(xh, Wth, Wph, bt_f, bp_f, boxes, relw, out2);

  if (use_ws){
    kh<true><<<2048, 512, 0, stream>>>(xh, Wgh, relw, gam, bet, out1, hnw);
    kreduce<<<3072, 256, 0, stream>>>(hnw, out1, 786432);
  } else {
    hipMemsetAsync(out1, 0, (size_t)512*12*1024*sizeof(float), stream);
    kh<false><<<2048, 512, 0, stream>>>(xh, Wgh, relw, gam, bet, out1, hnw);
  }
}

// Round 4
// 1362.079 us; speedup vs baseline: 2.3208x; 2.3208x over previous
//
#include <hip/hip_runtime.h>
#include <hip/hip_fp16.h>

typedef _Float16 f16;
typedef _Float16 f16x8 __attribute__((ext_vector_type(8)));
typedef _Float16 f16x4 __attribute__((ext_vector_type(4)));
typedef float    f32x4 __attribute__((ext_vector_type(4)));

__device__ __forceinline__ f32x4 mfma16(f16x8 a, f16x8 b, f32x4 c){
  return __builtin_amdgcn_mfma_f32_16x16x32_f16(a, b, c, 0, 0, 0);
}
__device__ __forceinline__ int imin(int a, int b){ return a < b ? a : b; }

// ---------------------------------------------------------------- f32 -> f16
__global__ void cvt_kernel(const float* __restrict__ src, f16* __restrict__ dst, int n4){
  int i = blockIdx.x * 256 + threadIdx.x;
  if (i < n4){
    float4 v = reinterpret_cast<const float4*>(src)[i];
    f16x4 h;
    h[0] = (f16)v.x; h[1] = (f16)v.y; h[2] = (f16)v.z; h[3] = (f16)v.w;
    reinterpret_cast<f16x4*>(dst)[i] = h;
  }
}

// ---------------------------------------------------------------- rel kernel
// grid: 2048 blocks = (bq in [0,128)) x (g in [0,16)), 256 threads (4 waves).
__global__ __launch_bounds__(256) void krel(
    const f16* __restrict__ xh, const f16* __restrict__ Wth, const f16* __restrict__ Wph,
    const float* __restrict__ bth, const float* __restrict__ bph,
    const float* __restrict__ boxes, float* __restrict__ relw, float* __restrict__ out2)
{
  const int bid  = blockIdx.x;
  const int slot = bid & 7, idx = bid >> 3;          // XCD swizzle: same g stays on one XCD
  const int g    = slot + ((idx >> 7) << 3);
  const int bq   = idx & 127;
  const int tid  = threadIdx.x;
  const int w    = tid >> 6, lane = tid & 63;
  const int l15  = lane & 15, l4 = lane >> 4;

  __shared__ f16 thS[48][264];
  __shared__ f16 phS[48][264];

  const f32x4 fz = {0.f, 0.f, 0.f, 0.f};
  f32x4 accT[3][4], accP[3][4];
  #pragma unroll
  for (int mt = 0; mt < 3; ++mt)
    #pragma unroll
    for (int j = 0; j < 4; ++j){ accT[mt][j] = fz; accP[mt][j] = fz; }

  const f16* Ab = xh  + (size_t)(bq*48 + l15)*1024 + l4*8;
  const f16* Tb = Wth + (size_t)(g*256 + w*64 + l15)*1024 + l4*8;
  const f16* Pb = Wph + (size_t)(g*256 + w*64 + l15)*1024 + l4*8;

  for (int kk = 0; kk < 32; ++kk){
    const int f = kk << 5;
    f16x8 a[3], bt[4], bp[4];
    #pragma unroll
    for (int mt = 0; mt < 3; ++mt) a[mt] = *(const f16x8*)(Ab + mt*16*1024 + f);
    #pragma unroll
    for (int j = 0; j < 4; ++j){
      bt[j] = *(const f16x8*)(Tb + j*16*1024 + f);
      bp[j] = *(const f16x8*)(Pb + j*16*1024 + f);
    }
    #pragma unroll
    for (int mt = 0; mt < 3; ++mt)
      #pragma unroll
      for (int j = 0; j < 4; ++j){
        accT[mt][j] = mfma16(a[mt], bt[j], accT[mt][j]);
        accP[mt][j] = mfma16(a[mt], bp[j], accP[mt][j]);
      }
  }

  #pragma unroll
  for (int j = 0; j < 4; ++j){
    const int ko = w*64 + j*16 + l15;
    const float bT = bth[g*256 + ko];
    const float bP = bph[g*256 + ko];
    #pragma unroll
    for (int mt = 0; mt < 3; ++mt)
      #pragma unroll
      for (int r = 0; r < 4; ++r){
        const int row = mt*16 + l4*4 + r;
        thS[row][ko] = (f16)(accT[mt][j][r] + bT);
        phS[row][ko] = (f16)(accP[mt][j][r] + bP);
      }
  }
  __syncthreads();

  const int bi = w;
  const int bglob = bq*4 + bi;
  f32x4 sa = fz;
  const int arow = imin(bi*12 + l15, 47);
  #pragma unroll
  for (int k8 = 0; k8 < 8; ++k8){
    const f16x8 a = *(const f16x8*)(&thS[arow][k8*32 + l4*8]);
    const f16x8 b = *(const f16x8*)(&phS[arow][k8*32 + l4*8]);
    sa = mfma16(a, b, sa);
  }
  const int m  = l15;
  const int mc = imin(m, 11);
  const float4 bxm = *(const float4*)(boxes + (size_t)(bglob*12 + mc)*4);
  const float cxm = (bxm.x + bxm.z)*0.5f, cym = (bxm.y + bxm.w)*0.5f;
  const float sqm = cxm*cxm + cym*cym;
  #pragma unroll
  for (int r = 0; r < 4; ++r){
    const int n  = l4*4 + r;
    const int nc = imin(n, 11);
    const float4 bxn = *(const float4*)(boxes + (size_t)(bglob*12 + nc)*4);
    const float cxn = (bxn.x + bxn.z)*0.5f, cyn = (bxn.y + bxn.w)*0.5f;
    const float sqn = cxn*cxn + cyn*cyn;
    const float dot = cxn*cxm + cyn*cym;
    const float d2  = (sqn - 2.f*dot) + sqm;
    const float dist = sqrtf(fmaxf(d2, 0.f));
    float val = sa[r] * 0.0625f;
    if (dist > 0.2f || m >= 12) val = -__builtin_inff();
    float mx = val;
    #pragma unroll
    for (int d = 1; d < 16; d <<= 1) mx = fmaxf(mx, __shfl_xor(mx, d));
    const float e = expf(val - mx);
    float s = e;
    #pragma unroll
    for (int d = 1; d < 16; d <<= 1) s += __shfl_xor(s, d);
    const float rv = e / s;
    if (n < 12 && m < 12){
      relw[((size_t)(bglob*16 + g))*144 + n*12 + m] = rv;
      if (g == 15) out2[(size_t)bglob*144 + n*12 + m] = rv;
    }
  }
}

// ---------------------------------------------------------------- h kernel
// WS=true : write post-LN/relu rows as f16 to hnw slot (no atomics).
//           grid = 128*p blocks, handles g in [g0, g0+p), p in {1,2,4,8,16}.
// WS=false: legacy atomicAdd path (fallback), grid 2048, p==16, g0==0.
template<bool WS>
__global__ __launch_bounds__(512) void kh(
    const f16* __restrict__ xh, const f16* __restrict__ Wgh,
    const float* __restrict__ relw, const float* __restrict__ gam,
    const float* __restrict__ bet, float* __restrict__ out1, f16* __restrict__ hnw,
    int g0, int p)
{
  const int bid = blockIdx.x;
  int g, bq, gslot;
  if (p == 16){
    const int slot = bid & 7, idx = bid >> 3;        // XCD swizzle
    g = slot + ((idx >> 7) << 3);
    bq = idx & 127;
    gslot = g;
  } else {
    // keep same-g-per-XCD: r = bid&7 maps to a fixed g_local per XCD
    const int r = bid & 7, q = bid >> 3;
    const int lp = (p == 8) ? 3 : (p == 4) ? 2 : (p == 2) ? 1 : 0;
    gslot = r & (p - 1);
    g = g0 + gslot;
    bq = q * (8 >> lp) + (r >> lp);
  }
  const int tid  = threadIdx.x;
  const int w    = tid >> 6, lane = tid & 63;
  const int l15  = lane & 15, l4 = lane >> 4;

  __shared__ f16   ylds[48][520];
  __shared__ float rel_s[4][144];
  __shared__ float stats[48][2];

  for (int t = tid; t < 576; t += 512){
    int bi = t / 144, nm = t % 144;
    rel_s[bi][nm] = relw[((size_t)((bq*4 + bi)*16 + g))*144 + nm];
  }

  const f32x4 fz = {0.f, 0.f, 0.f, 0.f};
  f32x4 acc[3][8];
  #pragma unroll
  for (int mt = 0; mt < 3; ++mt)
    #pragma unroll
    for (int j = 0; j < 8; ++j) acc[mt][j] = fz;

  const f16* Ab = xh  + (size_t)(bq*48 + l15)*1024 + l4*8;
  const f16* Bb = Wgh + (size_t)(g*1024 + w*128 + l15)*1024 + l4*8;

  for (int kk = 0; kk < 32; ++kk){
    const int f = kk << 5;
    f16x8 a[3], b[8];
    #pragma unroll
    for (int mt = 0; mt < 3; ++mt) a[mt] = *(const f16x8*)(Ab + mt*16*1024 + f);
    #pragma unroll
    for (int j = 0; j < 8; ++j)   b[j]  = *(const f16x8*)(Bb + j*16*1024 + f);
    #pragma unroll
    for (int mt = 0; mt < 3; ++mt)
      #pragma unroll
      for (int j = 0; j < 8; ++j)
        acc[mt][j] = mfma16(a[mt], b[j], acc[mt][j]);
  }
  __syncthreads();

  float srow[6], s2row[6];
  #pragma unroll
  for (int i = 0; i < 6; ++i){ srow[i] = 0.f; s2row[i] = 0.f; }

  #pragma unroll
  for (int half = 0; half < 2; ++half){
    if ((w >> 2) == half){
      const int ww = w & 3;
      #pragma unroll
      for (int mt = 0; mt < 3; ++mt)
        #pragma unroll
        for (int j = 0; j < 8; ++j){
          const int o = ww*128 + j*16 + l15;
          #pragma unroll
          for (int r = 0; r < 4; ++r)
            ylds[mt*16 + l4*4 + r][o] = (f16)acc[mt][j][r];
        }
    }
    __syncthreads();
    #pragma unroll
    for (int i = 0; i < 6; ++i){
      const int row = w*6 + i;
      const int bi = row / 12, n = row % 12;
      const float* rl = &rel_s[bi][n*12];
      float h[8];
      #pragma unroll
      for (int t = 0; t < 8; ++t) h[t] = 0.f;
      #pragma unroll
      for (int mm = 0; mm < 12; ++mm){
        const f16x8 yv = *(const f16x8*)(&ylds[bi*12 + mm][lane*8]);
        const float rv = rl[mm];
        #pragma unroll
        for (int t = 0; t < 8; ++t) h[t] = fmaf(rv, (float)yv[t], h[t]);
      }
      float ls = 0.f, l2 = 0.f;
      #pragma unroll
      for (int t = 0; t < 8; ++t){ ls += h[t]; l2 = fmaf(h[t], h[t], l2); }
      srow[i] += ls; s2row[i] += l2;
    }
    __syncthreads();
  }

  #pragma unroll
  for (int i = 0; i < 6; ++i){
    float s = srow[i], s2 = s2row[i];
    #pragma unroll
    for (int d = 1; d < 64; d <<= 1){
      s  += __shfl_xor(s, d);
      s2 += __shfl_xor(s2, d);
    }
    if (lane == 0){ stats[w*6 + i][0] = s; stats[w*6 + i][1] = s2; }
  }
  __syncthreads();

  #pragma unroll
  for (int pass = 0; pass < 2; ++pass){
    const int half = 1 - pass;
    if (pass == 1){
      if (w < 4){
        #pragma unroll
        for (int mt = 0; mt < 3; ++mt)
          #pragma unroll
          for (int j = 0; j < 8; ++j){
            const int o = w*128 + j*16 + l15;
            #pragma unroll
            for (int r = 0; r < 4; ++r)
              ylds[mt*16 + l4*4 + r][o] = (f16)acc[mt][j][r];
          }
      }
      __syncthreads();
    }
    const int obase = half*512 + lane*8;
    const float4 ga0 = *(const float4*)(gam + (size_t)g*1024 + obase);
    const float4 ga1 = *(const float4*)(gam + (size_t)g*1024 + obase + 4);
    const float4 be0 = *(const float4*)(bet + (size_t)g*1024 + obase);
    const float4 be1 = *(const float4*)(bet + (size_t)g*1024 + obase + 4);
    const float gv[8] = {ga0.x,ga0.y,ga0.z,ga0.w,ga1.x,ga1.y,ga1.z,ga1.w};
    const float bv[8] = {be0.x,be0.y,be0.z,be0.w,be1.x,be1.y,be1.z,be1.w};
    #pragma unroll
    for (int i = 0; i < 6; ++i){
      const int row = w*6 + i;
      const int bi = row / 12, n = row % 12;
      const float* rl = &rel_s[bi][n*12];
      float h[8];
      #pragma unroll
      for (int t = 0; t < 8; ++t) h[t] = 0.f;
      #pragma unroll
      for (int mm = 0; mm < 12; ++mm){
        const f16x8 yv = *(const f16x8*)(&ylds[bi*12 + mm][lane*8]);
        const float rv = rl[mm];
        #pragma unroll
        for (int t = 0; t < 8; ++t) h[t] = fmaf(rv, (float)yv[t], h[t]);
      }
      const float mu  = stats[row][0] * (1.f/1024.f);
      const float var = stats[row][1] * (1.f/1024.f) - mu*mu;
      const float rs  = rsqrtf(var + 1e-5f);
      if (WS){
        f16x8 hv;
        #pragma unroll
        for (int t = 0; t < 8; ++t){
          float v = (h[t] - mu)*rs*gv[t] + bv[t];
          hv[t] = (f16)fmaxf(v, 0.f);
        }
        *(f16x8*)(hnw + ((size_t)gslot*6144 + bq*48 + row)*1024 + obase) = hv;
      } else {
        float* op = out1 + (size_t)(bq*48 + row)*1024 + obase;
        #pragma unroll
        for (int t = 0; t < 8; ++t){
          float v = (h[t] - mu)*rs*gv[t] + bv[t];
          v = fmaxf(v, 0.f);
          atomicAdd(op + t, v);
        }
      }
    }
    if (pass == 0) __syncthreads();
  }
}

// ---------------------------------------------------------------- reduce over g-slots
// out1[i] = (first ? 0 : out1[i]) + sum_{s<p} hnw[s][i]; 8 floats per thread.
__global__ __launch_bounds__(256) void kreduce(const f16* __restrict__ hnw,
                                               float* __restrict__ out1,
                                               int p, int first, int n8){
  int i = blockIdx.x * 256 + threadIdx.x;
  if (i >= n8) return;
  float acc[8];
  #pragma unroll
  for (int t = 0; t < 8; ++t) acc[t] = 0.f;
  for (int s = 0; s < p; ++s){
    const f16x8 v = reinterpret_cast<const f16x8*>(hnw + (size_t)s*6291456)[i];
    #pragma unroll
    for (int t = 0; t < 8; ++t) acc[t] += (float)v[t];
  }
  if (!first){
    float4 p0 = reinterpret_cast<const float4*>(out1)[i*2];
    float4 p1 = reinterpret_cast<const float4*>(out1)[i*2 + 1];
    acc[0]+=p0.x; acc[1]+=p0.y; acc[2]+=p0.z; acc[3]+=p0.w;
    acc[4]+=p1.x; acc[5]+=p1.y; acc[6]+=p1.z; acc[7]+=p1.w;
  }
  float4 o0 = {acc[0], acc[1], acc[2], acc[3]};
  float4 o1 = {acc[4], acc[5], acc[6], acc[7]};
  reinterpret_cast<float4*>(out1)[i*2]     = o0;
  reinterpret_cast<float4*>(out1)[i*2 + 1] = o1;
}

// ---------------------------------------------------------------- launcher
extern "C" void kernel_launch(void* const* d_in, const int* in_sizes, int n_in,
                              void* d_out, int out_size, void* d_ws, size_t ws_size,
                              hipStream_t stream)
{
  const float* x_f   = (const float*)d_in[0];
  const float* boxes = (const float*)d_in[1];
  const float* Wt_f  = (const float*)d_in[2];
  const float* bt_f  = (const float*)d_in[3];
  const float* Wp_f  = (const float*)d_in[4];
  const float* bp_f  = (const float*)d_in[5];
  const float* Wg_f  = (const float*)d_in[6];
  const float* gam   = (const float*)d_in[7];
  const float* bet   = (const float*)d_in[8];

  float* out1 = (float*)d_out;
  float* out2 = out1 + (size_t)512*12*1024;

  // layout: persistent [xh | Wgh | relw] then pool.
  // pool head holds Wth/Wph during krel; reused as hnw slots afterwards
  // (stream order guarantees krel completes before first kh).
  char* ws = (char*)d_ws;
  f16*  xh   = (f16*)(ws);                       // 12,582,912 B
  f16*  Wgh  = (f16*)(ws + 12582912);            // 33,554,432 B
  float* relw = (float*)(ws + 46137344);         //  4,718,592 B
  char* pool = ws + 50855936;
  f16*  Wth  = (f16*)(pool);                     //  8,388,608 B (krel only)
  f16*  Wph  = (f16*)(pool + 8388608);           //  8,388,608 B (krel only)
  f16*  hnw  = (f16*)(pool);                     // p * 12,582,912 B (post-krel)

  const size_t slot_bytes = 12582912u;
  size_t avail = (ws_size > 50855936u) ? ws_size - 50855936u : 0u;
  // need Wth+Wph resident too: pool must hold at least 16.8 MB for krel
  const bool krel_fit = avail >= 16777216u;
  int p = 16;
  while (p > 1 && (size_t)p * slot_bytes > avail) p >>= 1;
  const bool use_ws = krel_fit && (avail >= slot_bytes);

  cvt_kernel<<<6144,  256, 0, stream>>>(x_f,  xh,  6291456/4);
  cvt_kernel<<<16384, 256, 0, stream>>>(Wg_f, Wgh, 16777216/4);
  cvt_kernel<<<4096,  256, 0, stream>>>(Wt_f, Wth, 4194304/4);
  cvt_kernel<<<4096,  256, 0, stream>>>(Wp_f, Wph, 4194304/4);

  krel<<<2048, 256, 0, stream>>>(xh, Wth, Wph, bt_f, bp_f, boxes, relw, out2);

  if (use_ws){
    int first = 1;
    for (int g0 = 0; g0 < 16; g0 += p){
      kh<true><<<128*p, 512, 0, stream>>>(xh, Wgh, relw, gam, bet, out1, hnw, g0, p);
      kreduce<<<3072, 256, 0, stream>>>(hnw, out1, p, first, 786432);
      first = 0;
    }
  } else {
    hipMemsetAsync(out1, 0, (size_t)512*12*1024*sizeof(float), stream);
    kh<false><<<2048, 512, 0, stream>>>(xh, Wgh, relw, gam, bet, out1, hnw, 0, 16);
  }
}

// Round 5
// 1116.279 us; speedup vs baseline: 2.8319x; 1.2202x over previous
//
#include <hip/hip_runtime.h>
#include <hip/hip_fp16.h>

typedef _Float16 f16;
typedef _Float16 f16x8 __attribute__((ext_vector_type(8)));
typedef _Float16 f16x4 __attribute__((ext_vector_type(4)));
typedef float    f32x4 __attribute__((ext_vector_type(4)));

__device__ __forceinline__ f32x4 mfma16(f16x8 a, f16x8 b, f32x4 c){
  return __builtin_amdgcn_mfma_f32_16x16x32_f16(a, b, c, 0, 0, 0);
}
__device__ __forceinline__ int imin(int a, int b){ return a < b ? a : b; }

// async global->LDS, 16B per lane; dest = wave-uniform base + lane*16
__device__ __forceinline__ void gload_lds16(const f16* g, f16* l){
  __builtin_amdgcn_global_load_lds(
      (const __attribute__((address_space(1))) void*)g,
      (__attribute__((address_space(3))) void*)l, 16, 0, 0);
}

// ---------------------------------------------------------------- f32 -> f16
__global__ void cvt_kernel(const float* __restrict__ src, f16* __restrict__ dst, int n4){
  int i = blockIdx.x * 256 + threadIdx.x;
  if (i < n4){
    float4 v = reinterpret_cast<const float4*>(src)[i];
    f16x4 h;
    h[0] = (f16)v.x; h[1] = (f16)v.y; h[2] = (f16)v.z; h[3] = (f16)v.w;
    reinterpret_cast<f16x4*>(dst)[i] = h;
  }
}

// ---------------------------------------------------------------- rel kernel
// grid: 2048 blocks = (bq in [0,128)) x (g in [0,16)), 256 threads (4 waves).
// A-tile (48x1024 xh rows) staged per half-K into LDS via global_load_lds;
// stage buffer is reused as thS/phS in the epilogue (disjoint phases).
__global__ __launch_bounds__(256) void krel(
    const f16* __restrict__ xh, const f16* __restrict__ Wth, const f16* __restrict__ Wph,
    const float* __restrict__ bth, const float* __restrict__ bph,
    const float* __restrict__ boxes, float* __restrict__ relw, float* __restrict__ out2)
{
  const int bid  = blockIdx.x;
  const int slot = bid & 7, idx = bid >> 3;          // XCD swizzle: same g stays on one XCD
  const int g    = slot + ((idx >> 7) << 3);
  const int bq   = idx & 127;
  const int tid  = threadIdx.x;
  const int w    = tid >> 6, lane = tid & 63;
  const int l15  = lane & 15, l4 = lane >> 4;

  // 48*528 f16 = 50688 B. GEMM phase: A-stage [48][528] (512 data + 16 pad).
  // Epilogue: thS = rows of [48][264] at stageS, phS at stageS + 48*264.
  __shared__ f16 stageS[48*528];
  f16* thS = stageS;             // [48][264] flat
  f16* phS = stageS + 48*264;    // [48][264] flat

  const f32x4 fz = {0.f, 0.f, 0.f, 0.f};
  f32x4 accT[3][4], accP[3][4];
  #pragma unroll
  for (int mt = 0; mt < 3; ++mt)
    #pragma unroll
    for (int j = 0; j < 4; ++j){ accT[mt][j] = fz; accP[mt][j] = fz; }

  const f16* Tb = Wth + (size_t)(g*256 + w*64 + l15)*1024 + l4*8;
  const f16* Pb = Wph + (size_t)(g*256 + w*64 + l15)*1024 + l4*8;

  #pragma unroll
  for (int half = 0; half < 2; ++half){
    if (half) __syncthreads();               // readers of previous half done
    // wave w stages rows w*12 .. w*12+11 (one 1024B row per instruction)
    #pragma unroll
    for (int r = 0; r < 12; ++r){
      const int row = w*12 + r;
      gload_lds16(xh + (size_t)(bq*48 + row)*1024 + half*512 + lane*8,
                  &stageS[row*528]);
    }
    __syncthreads();                         // drain vmcnt; stage visible
    #pragma unroll 2
    for (int kk = 0; kk < 16; ++kk){
      const int fB = (half*16 + kk) << 5;
      f16x8 a[3], bt[4], bp[4];
      #pragma unroll
      for (int mt = 0; mt < 3; ++mt)
        a[mt] = *(const f16x8*)(&stageS[(mt*16 + l15)*528 + kk*32 + l4*8]);
      #pragma unroll
      for (int j = 0; j < 4; ++j){
        bt[j] = *(const f16x8*)(Tb + j*16*1024 + fB);
        bp[j] = *(const f16x8*)(Pb + j*16*1024 + fB);
      }
      #pragma unroll
      for (int mt = 0; mt < 3; ++mt)
        #pragma unroll
        for (int j = 0; j < 4; ++j){
          accT[mt][j] = mfma16(a[mt], bt[j], accT[mt][j]);
          accP[mt][j] = mfma16(a[mt], bp[j], accP[mt][j]);
        }
    }
  }
  __syncthreads();   // all reads of stageS done; safe to write thS/phS

  #pragma unroll
  for (int j = 0; j < 4; ++j){
    const int ko = w*64 + j*16 + l15;
    const float bT = bth[g*256 + ko];
    const float bP = bph[g*256 + ko];
    #pragma unroll
    for (int mt = 0; mt < 3; ++mt)
      #pragma unroll
      for (int r = 0; r < 4; ++r){
        const int row = mt*16 + l4*4 + r;
        thS[row*264 + ko] = (f16)(accT[mt][j][r] + bT);
        phS[row*264 + ko] = (f16)(accP[mt][j][r] + bP);
      }
  }
  __syncthreads();

  const int bi = w;
  const int bglob = bq*4 + bi;
  f32x4 sa = fz;
  const int arow = imin(bi*12 + l15, 47);
  #pragma unroll
  for (int k8 = 0; k8 < 8; ++k8){
    const f16x8 a = *(const f16x8*)(&thS[arow*264 + k8*32 + l4*8]);
    const f16x8 b = *(const f16x8*)(&phS[arow*264 + k8*32 + l4*8]);
    sa = mfma16(a, b, sa);
  }
  const int m  = l15;
  const int mc = imin(m, 11);
  const float4 bxm = *(const float4*)(boxes + (size_t)(bglob*12 + mc)*4);
  const float cxm = (bxm.x + bxm.z)*0.5f, cym = (bxm.y + bxm.w)*0.5f;
  const float sqm = cxm*cxm + cym*cym;
  #pragma unroll
  for (int r = 0; r < 4; ++r){
    const int n  = l4*4 + r;
    const int nc = imin(n, 11);
    const float4 bxn = *(const float4*)(boxes + (size_t)(bglob*12 + nc)*4);
    const float cxn = (bxn.x + bxn.z)*0.5f, cyn = (bxn.y + bxn.w)*0.5f;
    const float sqn = cxn*cxn + cyn*cyn;
    const float dot = cxn*cxm + cyn*cym;
    const float d2  = (sqn - 2.f*dot) + sqm;
    const float dist = sqrtf(fmaxf(d2, 0.f));
    float val = sa[r] * 0.0625f;
    if (dist > 0.2f || m >= 12) val = -__builtin_inff();
    float mx = val;
    #pragma unroll
    for (int d = 1; d < 16; d <<= 1) mx = fmaxf(mx, __shfl_xor(mx, d));
    const float e = expf(val - mx);
    float s = e;
    #pragma unroll
    for (int d = 1; d < 16; d <<= 1) s += __shfl_xor(s, d);
    const float rv = e / s;
    if (n < 12 && m < 12){
      relw[((size_t)(bglob*16 + g))*144 + n*12 + m] = rv;
      if (g == 15) out2[(size_t)bglob*144 + n*12 + m] = rv;
    }
  }
}

// ---------------------------------------------------------------- h kernel
// grid = 128*p blocks, 512 threads (8 waves). A staged per half-K via
// global_load_lds into buf; buf reused as ylds in epilogue.
// WS=true : write post-LN/relu rows as f16 to hnw slot (no atomics).
// WS=false: legacy atomicAdd fallback.
template<bool WS>
__global__ __launch_bounds__(512) void kh(
    const f16* __restrict__ xh, const f16* __restrict__ Wgh,
    const float* __restrict__ relw, const float* __restrict__ gam,
    const float* __restrict__ bet, float* __restrict__ out1, f16* __restrict__ hnw,
    int g0, int p)
{
  const int bid = blockIdx.x;
  int g, bq, gslot;
  if (p == 16){
    const int slot = bid & 7, idx = bid >> 3;        // XCD swizzle
    g = slot + ((idx >> 7) << 3);
    bq = idx & 127;
    gslot = g;
  } else {
    const int r = bid & 7, q = bid >> 3;
    const int lp = (p == 8) ? 3 : (p == 4) ? 2 : (p == 2) ? 1 : 0;
    gslot = r & (p - 1);
    g = g0 + gslot;
    bq = q * (8 >> lp) + (r >> lp);
  }
  const int tid  = threadIdx.x;
  const int w    = tid >> 6, lane = tid & 63;
  const int l15  = lane & 15, l4 = lane >> 4;

  __shared__ f16   buf[48*520];   // GEMM: A-stage half-K; epilogue: ylds
  __shared__ float rel_s[4][144];
  __shared__ float stats[48][2];

  const f32x4 fz = {0.f, 0.f, 0.f, 0.f};
  f32x4 acc[3][8];
  #pragma unroll
  for (int mt = 0; mt < 3; ++mt)
    #pragma unroll
    for (int j = 0; j < 8; ++j) acc[mt][j] = fz;

  const f16* Bb = Wgh + (size_t)(g*1024 + w*128 + l15)*1024 + l4*8;

  #pragma unroll
  for (int half = 0; half < 2; ++half){
    if (half) __syncthreads();               // readers of previous half done
    #pragma unroll
    for (int r = 0; r < 6; ++r){
      const int row = w*6 + r;
      gload_lds16(xh + (size_t)(bq*48 + row)*1024 + half*512 + lane*8,
                  &buf[row*520]);
    }
    if (half == 0){
      for (int t = tid; t < 576; t += 512){
        int bi = t / 144, nm = t % 144;
        rel_s[bi][nm] = relw[((size_t)((bq*4 + bi)*16 + g))*144 + nm];
      }
    }
    __syncthreads();                         // drain vmcnt; stage visible
    #pragma unroll 2
    for (int kk = 0; kk < 16; ++kk){
      const int fB = (half*16 + kk) << 5;
      f16x8 a[3], b[8];
      #pragma unroll
      for (int mt = 0; mt < 3; ++mt)
        a[mt] = *(const f16x8*)(&buf[(mt*16 + l15)*520 + kk*32 + l4*8]);
      #pragma unroll
      for (int j = 0; j < 8; ++j)
        b[j] = *(const f16x8*)(Bb + j*16*1024 + fB);
      #pragma unroll
      for (int mt = 0; mt < 3; ++mt)
        #pragma unroll
        for (int j = 0; j < 8; ++j)
          acc[mt][j] = mfma16(a[mt], b[j], acc[mt][j]);
    }
  }
  __syncthreads();   // A-stage reads done; buf becomes ylds

  float srow[6], s2row[6];
  #pragma unroll
  for (int i = 0; i < 6; ++i){ srow[i] = 0.f; s2row[i] = 0.f; }

  // two halves of o: write y->LDS (f16), accumulate LN stats
  #pragma unroll
  for (int half = 0; half < 2; ++half){
    if ((w >> 2) == half){
      const int ww = w & 3;
      #pragma unroll
      for (int mt = 0; mt < 3; ++mt)
        #pragma unroll
        for (int j = 0; j < 8; ++j){
          const int o = ww*128 + j*16 + l15;
          #pragma unroll
          for (int r = 0; r < 4; ++r)
            buf[(mt*16 + l4*4 + r)*520 + o] = (f16)acc[mt][j][r];
        }
    }
    __syncthreads();
    #pragma unroll
    for (int i = 0; i < 6; ++i){
      const int row = w*6 + i;
      const int bi = row / 12, n = row % 12;
      const float* rl = &rel_s[bi][n*12];
      float h[8];
      #pragma unroll
      for (int t = 0; t < 8; ++t) h[t] = 0.f;
      #pragma unroll
      for (int mm = 0; mm < 12; ++mm){
        const f16x8 yv = *(const f16x8*)(&buf[(bi*12 + mm)*520 + lane*8]);
        const float rv = rl[mm];
        #pragma unroll
        for (int t = 0; t < 8; ++t) h[t] = fmaf(rv, (float)yv[t], h[t]);
      }
      float ls = 0.f, l2 = 0.f;
      #pragma unroll
      for (int t = 0; t < 8; ++t){ ls += h[t]; l2 = fmaf(h[t], h[t], l2); }
      srow[i] += ls; s2row[i] += l2;
    }
    __syncthreads();
  }

  #pragma unroll
  for (int i = 0; i < 6; ++i){
    float s = srow[i], s2 = s2row[i];
    #pragma unroll
    for (int d = 1; d < 64; d <<= 1){
      s  += __shfl_xor(s, d);
      s2 += __shfl_xor(s2, d);
    }
    if (lane == 0){ stats[w*6 + i][0] = s; stats[w*6 + i][1] = s2; }
  }
  __syncthreads();

  #pragma unroll
  for (int pass = 0; pass < 2; ++pass){
    const int half = 1 - pass;
    if (pass == 1){
      if (w < 4){
        #pragma unroll
        for (int mt = 0; mt < 3; ++mt)
          #pragma unroll
          for (int j = 0; j < 8; ++j){
            const int o = w*128 + j*16 + l15;
            #pragma unroll
            for (int r = 0; r < 4; ++r)
              buf[(mt*16 + l4*4 + r)*520 + o] = (f16)acc[mt][j][r];
          }
      }
      __syncthreads();
    }
    const int obase = half*512 + lane*8;
    const float4 ga0 = *(const float4*)(gam + (size_t)g*1024 + obase);
    const float4 ga1 = *(const float4*)(gam + (size_t)g*1024 + obase + 4);
    const float4 be0 = *(const float4*)(bet + (size_t)g*1024 + obase);
    const float4 be1 = *(const float4*)(bet + (size_t)g*1024 + obase + 4);
    const float gv[8] = {ga0.x,ga0.y,ga0.z,ga0.w,ga1.x,ga1.y,ga1.z,ga1.w};
    const float bv[8] = {be0.x,be0.y,be0.z,be0.w,be1.x,be1.y,be1.z,be1.w};
    #pragma unroll
    for (int i = 0; i < 6; ++i){
      const int row = w*6 + i;
      const int bi = row / 12, n = row % 12;
      const float* rl = &rel_s[bi][n*12];
      float h[8];
      #pragma unroll
      for (int t = 0; t < 8; ++t) h[t] = 0.f;
      #pragma unroll
      for (int mm = 0; mm < 12; ++mm){
        const f16x8 yv = *(const f16x8*)(&buf[(bi*12 + mm)*520 + lane*8]);
        const float rv = rl[mm];
        #pragma unroll
        for (int t = 0; t < 8; ++t) h[t] = fmaf(rv, (float)yv[t], h[t]);
      }
      const float mu  = stats[row][0] * (1.f/1024.f);
      const float var = stats[row][1] * (1.f/1024.f) - mu*mu;
      const float rs  = rsqrtf(var + 1e-5f);
      if (WS){
        f16x8 hv;
        #pragma unroll
        for (int t = 0; t < 8; ++t){
          float v = (h[t] - mu)*rs*gv[t] + bv[t];
          hv[t] = (f16)fmaxf(v, 0.f);
        }
        *(f16x8*)(hnw + ((size_t)gslot*6144 + bq*48 + row)*1024 + obase) = hv;
      } else {
        float* op = out1 + (size_t)(bq*48 + row)*1024 + obase;
        #pragma unroll
        for (int t = 0; t < 8; ++t){
          float v = (h[t] - mu)*rs*gv[t] + bv[t];
          v = fmaxf(v, 0.f);
          atomicAdd(op + t, v);
        }
      }
    }
    if (pass == 0) __syncthreads();
  }
}

// ---------------------------------------------------------------- reduce over g-slots
__global__ __launch_bounds__(256) void kreduce(const f16* __restrict__ hnw,
                                               float* __restrict__ out1,
                                               int p, int first, int n8){
  int i = blockIdx.x * 256 + threadIdx.x;
  if (i >= n8) return;
  float acc[8];
  #pragma unroll
  for (int t = 0; t < 8; ++t) acc[t] = 0.f;
  for (int s = 0; s < p; ++s){
    const f16x8 v = reinterpret_cast<const f16x8*>(hnw + (size_t)s*6291456)[i];
    #pragma unroll
    for (int t = 0; t < 8; ++t) acc[t] += (float)v[t];
  }
  if (!first){
    float4 p0 = reinterpret_cast<const float4*>(out1)[i*2];
    float4 p1 = reinterpret_cast<const float4*>(out1)[i*2 + 1];
    acc[0]+=p0.x; acc[1]+=p0.y; acc[2]+=p0.z; acc[3]+=p0.w;
    acc[4]+=p1.x; acc[5]+=p1.y; acc[6]+=p1.z; acc[7]+=p1.w;
  }
  float4 o0 = {acc[0], acc[1], acc[2], acc[3]};
  float4 o1 = {acc[4], acc[5], acc[6], acc[7]};
  reinterpret_cast<float4*>(out1)[i*2]     = o0;
  reinterpret_cast<float4*>(out1)[i*2 + 1] = o1;
}

// ---------------------------------------------------------------- launcher
extern "C" void kernel_launch(void* const* d_in, const int* in_sizes, int n_in,
                              void* d_out, int out_size, void* d_ws, size_t ws_size,
                              hipStream_t stream)
{
  const float* x_f   = (const float*)d_in[0];
  const float* boxes = (const float*)d_in[1];
  const float* Wt_f  = (const float*)d_in[2];
  const float* bt_f  = (const float*)d_in[3];
  const float* Wp_f  = (const float*)d_in[4];
  const float* bp_f  = (const float*)d_in[5];
  const float* Wg_f  = (const float*)d_in[6];
  const float* gam   = (const float*)d_in[7];
  const float* bet   = (const float*)d_in[8];

  float* out1 = (float*)d_out;
  float* out2 = out1 + (size_t)512*12*1024;

  // layout: persistent [xh | Wgh | relw] then pool.
  // pool head holds Wth/Wph during krel; reused as hnw slots afterwards.
  char* ws = (char*)d_ws;
  f16*  xh   = (f16*)(ws);                       // 12,582,912 B
  f16*  Wgh  = (f16*)(ws + 12582912);            // 33,554,432 B
  float* relw = (float*)(ws + 46137344);         //  4,718,592 B
  char* pool = ws + 50855936;
  f16*  Wth  = (f16*)(pool);                     //  8,388,608 B (krel only)
  f16*  Wph  = (f16*)(pool + 8388608);           //  8,388,608 B (krel only)
  f16*  hnw  = (f16*)(pool);                     // p * 12,582,912 B (post-krel)

  const size_t slot_bytes = 12582912u;
  size_t avail = (ws_size > 50855936u) ? ws_size - 50855936u : 0u;
  const bool krel_fit = avail >= 16777216u;
  int p = 16;
  while (p > 1 && (size_t)p * slot_bytes > avail) p >>= 1;
  const bool use_ws = krel_fit && (avail >= slot_bytes);

  cvt_kernel<<<6144,  256, 0, stream>>>(x_f,  xh,  6291456/4);
  cvt_kernel<<<16384, 256, 0, stream>>>(Wg_f, Wgh, 16777216/4);
  cvt_kernel<<<4096,  256, 0, stream>>>(Wt_f, Wth, 4194304/4);
  cvt_kernel<<<4096,  256, 0, stream>>>(Wp_f, Wph, 4194304/4);

  krel<<<2048, 256, 0, stream>>>(xh, Wth, Wph, bt_f, bp_f, boxes, relw, out2);

  if (use_ws){
    int first = 1;
    for (int g0 = 0; g0 < 16; g0 += p){
      kh<true><<<128*p, 512, 0, stream>>>(xh, Wgh, relw, gam, bet, out1, hnw, g0, p);
      kreduce<<<3072, 256, 0, stream>>>(hnw, out1, p, first, 786432);
      first = 0;
    }
  } else {
    hipMemsetAsync(out1, 0, (size_t)512*12*1024*sizeof(float), stream);
    kh<false><<<2048, 512, 0, stream>>>(xh, Wgh, relw, gam, bet, out1, hnw, 0, 16);
  }
}

// Round 6
// 1047.303 us; speedup vs baseline: 3.0184x; 1.0659x over previous
//
#include <hip/hip_runtime.h>
#include <hip/hip_fp16.h>

typedef _Float16 f16;
typedef _Float16 f16x8 __attribute__((ext_vector_type(8)));
typedef _Float16 f16x4 __attribute__((ext_vector_type(4)));
typedef float    f32x4 __attribute__((ext_vector_type(4)));

__device__ __forceinline__ f32x4 mfma16(f16x8 a, f16x8 b, f32x4 c){
  return __builtin_amdgcn_mfma_f32_16x16x32_f16(a, b, c, 0, 0, 0);
}
__device__ __forceinline__ int imin(int a, int b){ return a < b ? a : b; }

// async global->LDS, 16B per lane; dest = wave-uniform base + lane*16
__device__ __forceinline__ void gload_lds16(const f16* g, f16* l){
  __builtin_amdgcn_global_load_lds(
      (const __attribute__((address_space(1))) void*)g,
      (__attribute__((address_space(3))) void*)l, 16, 0, 0);
}

// ---------------------------------------------------------------- f32 -> f16
__global__ void cvt_kernel(const float* __restrict__ src, f16* __restrict__ dst, int n4){
  int i = blockIdx.x * 256 + threadIdx.x;
  if (i < n4){
    float4 v = reinterpret_cast<const float4*>(src)[i];
    f16x4 h;
    h[0] = (f16)v.x; h[1] = (f16)v.y; h[2] = (f16)v.z; h[3] = (f16)v.w;
    reinterpret_cast<f16x4*>(dst)[i] = h;
  }
}

// ---------------------------------------------------------------- rel kernel
// grid: 2048 blocks = (bq in [0,128)) x (g in [0,16)), 256 threads (4 waves).
__global__ __launch_bounds__(256) void krel(
    const f16* __restrict__ xh, const f16* __restrict__ Wth, const f16* __restrict__ Wph,
    const float* __restrict__ bth, const float* __restrict__ bph,
    const float* __restrict__ boxes, float* __restrict__ relw, float* __restrict__ out2)
{
  const int bid  = blockIdx.x;
  const int slot = bid & 7, idx = bid >> 3;          // XCD swizzle: same g stays on one XCD
  const int g    = slot + ((idx >> 7) << 3);
  const int bq   = idx & 127;
  const int tid  = threadIdx.x;
  const int w    = tid >> 6, lane = tid & 63;
  const int l15  = lane & 15, l4 = lane >> 4;

  __shared__ f16 stageS[48*528];
  f16* thS = stageS;             // [48][264] flat (epilogue)
  f16* phS = stageS + 48*264;    // [48][264] flat

  const f32x4 fz = {0.f, 0.f, 0.f, 0.f};
  f32x4 accT[3][4], accP[3][4];
  #pragma unroll
  for (int mt = 0; mt < 3; ++mt)
    #pragma unroll
    for (int j = 0; j < 4; ++j){ accT[mt][j] = fz; accP[mt][j] = fz; }

  const f16* Tb = Wth + (size_t)(g*256 + w*64 + l15)*1024 + l4*8;
  const f16* Pb = Wph + (size_t)(g*256 + w*64 + l15)*1024 + l4*8;

  #pragma unroll
  for (int half = 0; half < 2; ++half){
    if (half) __syncthreads();
    #pragma unroll
    for (int r = 0; r < 12; ++r){
      const int row = w*12 + r;
      gload_lds16(xh + (size_t)(bq*48 + row)*1024 + half*512 + lane*8,
                  &stageS[row*528]);
    }
    __syncthreads();
    #pragma unroll 2
    for (int kk = 0; kk < 16; ++kk){
      const int fB = (half*16 + kk) << 5;
      f16x8 a[3], bt[4], bp[4];
      #pragma unroll
      for (int mt = 0; mt < 3; ++mt)
        a[mt] = *(const f16x8*)(&stageS[(mt*16 + l15)*528 + kk*32 + l4*8]);
      #pragma unroll
      for (int j = 0; j < 4; ++j){
        bt[j] = *(const f16x8*)(Tb + j*16*1024 + fB);
        bp[j] = *(const f16x8*)(Pb + j*16*1024 + fB);
      }
      #pragma unroll
      for (int mt = 0; mt < 3; ++mt)
        #pragma unroll
        for (int j = 0; j < 4; ++j){
          accT[mt][j] = mfma16(a[mt], bt[j], accT[mt][j]);
          accP[mt][j] = mfma16(a[mt], bp[j], accP[mt][j]);
        }
    }
  }
  __syncthreads();

  #pragma unroll
  for (int j = 0; j < 4; ++j){
    const int ko = w*64 + j*16 + l15;
    const float bT = bth[g*256 + ko];
    const float bP = bph[g*256 + ko];
    #pragma unroll
    for (int mt = 0; mt < 3; ++mt)
      #pragma unroll
      for (int r = 0; r < 4; ++r){
        const int row = mt*16 + l4*4 + r;
        thS[row*264 + ko] = (f16)(accT[mt][j][r] + bT);
        phS[row*264 + ko] = (f16)(accP[mt][j][r] + bP);
      }
  }
  __syncthreads();

  const int bi = w;
  const int bglob = bq*4 + bi;
  f32x4 sa = fz;
  const int arow = imin(bi*12 + l15, 47);
  #pragma unroll
  for (int k8 = 0; k8 < 8; ++k8){
    const f16x8 a = *(const f16x8*)(&thS[arow*264 + k8*32 + l4*8]);
    const f16x8 b = *(const f16x8*)(&phS[arow*264 + k8*32 + l4*8]);
    sa = mfma16(a, b, sa);
  }
  const int m  = l15;
  const int mc = imin(m, 11);
  const float4 bxm = *(const float4*)(boxes + (size_t)(bglob*12 + mc)*4);
  const float cxm = (bxm.x + bxm.z)*0.5f, cym = (bxm.y + bxm.w)*0.5f;
  const float sqm = cxm*cxm + cym*cym;
  #pragma unroll
  for (int r = 0; r < 4; ++r){
    const int n  = l4*4 + r;
    const int nc = imin(n, 11);
    const float4 bxn = *(const float4*)(boxes + (size_t)(bglob*12 + nc)*4);
    const float cxn = (bxn.x + bxn.z)*0.5f, cyn = (bxn.y + bxn.w)*0.5f;
    const float sqn = cxn*cxn + cyn*cyn;
    const float dot = cxn*cxm + cyn*cym;
    const float d2  = (sqn - 2.f*dot) + sqm;
    const float dist = sqrtf(fmaxf(d2, 0.f));
    float val = sa[r] * 0.0625f;
    if (dist > 0.2f || m >= 12) val = -__builtin_inff();
    float mx = val;
    #pragma unroll
    for (int d = 1; d < 16; d <<= 1) mx = fmaxf(mx, __shfl_xor(mx, d));
    const float e = expf(val - mx);
    float s = e;
    #pragma unroll
    for (int d = 1; d < 16; d <<= 1) s += __shfl_xor(s, d);
    const float rv = e / s;
    if (n < 12 && m < 12){
      relw[((size_t)(bglob*16 + g))*144 + n*12 + m] = rv;
      if (g == 15) out2[(size_t)bglob*144 + n*12 + m] = rv;
    }
  }
}

// ---------------------------------------------------------------- h kernel
// grid = 128*p blocks, 512 threads (8 waves). A staged per half-K via
// global_load_lds into buf; buf reused as y (one 512-col half at a time).
// Epilogue: y cached to regs (12 f16x8 per half), h computed ONCE per row
// with wave-shfl LN stats, normalized immediately, stored (no atomics).
template<bool WS>
__global__ __launch_bounds__(512) void kh(
    const f16* __restrict__ xh, const f16* __restrict__ Wgh,
    const float* __restrict__ relw, const float* __restrict__ gam,
    const float* __restrict__ bet, float* __restrict__ out1, f16* __restrict__ hnw,
    int g0, int p)
{
  const int bid = blockIdx.x;
  int g, bq, gslot;
  if (p == 16){
    const int slot = bid & 7, idx = bid >> 3;        // XCD swizzle
    g = slot + ((idx >> 7) << 3);
    bq = idx & 127;
    gslot = g;
  } else {
    const int r = bid & 7, q = bid >> 3;
    const int lp = (p == 8) ? 3 : (p == 4) ? 2 : (p == 2) ? 1 : 0;
    gslot = r & (p - 1);
    g = g0 + gslot;
    bq = q * (8 >> lp) + (r >> lp);
  }
  const int tid  = threadIdx.x;
  const int w    = tid >> 6, lane = tid & 63;
  const int l15  = lane & 15, l4 = lane >> 4;

  __shared__ f16   buf[48*520];   // GEMM: A-stage half-K; epilogue: y half
  __shared__ float rel_s[4][144];

  const f32x4 fz = {0.f, 0.f, 0.f, 0.f};
  f32x4 acc[3][8];
  #pragma unroll
  for (int mt = 0; mt < 3; ++mt)
    #pragma unroll
    for (int j = 0; j < 8; ++j) acc[mt][j] = fz;

  const f16* Bb = Wgh + (size_t)(g*1024 + w*128 + l15)*1024 + l4*8;

  #pragma unroll
  for (int half = 0; half < 2; ++half){
    if (half) __syncthreads();
    #pragma unroll
    for (int r = 0; r < 6; ++r){
      const int row = w*6 + r;
      gload_lds16(xh + (size_t)(bq*48 + row)*1024 + half*512 + lane*8,
                  &buf[row*520]);
    }
    if (half == 0){
      for (int t = tid; t < 576; t += 512){
        int bi = t / 144, nm = t % 144;
        rel_s[bi][nm] = relw[((size_t)((bq*4 + bi)*16 + g))*144 + nm];
      }
    }
    __syncthreads();
    #pragma unroll 2
    for (int kk = 0; kk < 16; ++kk){
      const int fB = (half*16 + kk) << 5;
      f16x8 a[3], b[8];
      #pragma unroll
      for (int mt = 0; mt < 3; ++mt)
        a[mt] = *(const f16x8*)(&buf[(mt*16 + l15)*520 + kk*32 + l4*8]);
      #pragma unroll
      for (int j = 0; j < 8; ++j)
        b[j] = *(const f16x8*)(Bb + j*16*1024 + fB);
      #pragma unroll
      for (int mt = 0; mt < 3; ++mt)
        #pragma unroll
        for (int j = 0; j < 8; ++j)
          acc[mt][j] = mfma16(a[mt], b[j], acc[mt][j]);
    }
  }
  __syncthreads();   // A-stage reads done; buf becomes y

  const int bi = w >> 1;             // batch handled by this wave (rows w*6..w*6+5)

  // ---- write y half0 (cols 0..511) from waves 0-3; cache to regs
  if (w < 4){
    #pragma unroll
    for (int mt = 0; mt < 3; ++mt)
      #pragma unroll
      for (int j = 0; j < 8; ++j){
        const int o = w*128 + j*16 + l15;
        #pragma unroll
        for (int r = 0; r < 4; ++r)
          buf[(mt*16 + l4*4 + r)*520 + o] = (f16)acc[mt][j][r];
      }
  }
  __syncthreads();
  f16x8 y0[12];
  #pragma unroll
  for (int mm = 0; mm < 12; ++mm)
    y0[mm] = *(const f16x8*)(&buf[(bi*12 + mm)*520 + lane*8]);
  __syncthreads();

  // ---- write y half1 (cols 512..1023) from waves 4-7; cache to regs
  if (w >= 4){
    #pragma unroll
    for (int mt = 0; mt < 3; ++mt)
      #pragma unroll
      for (int j = 0; j < 8; ++j){
        const int o = (w - 4)*128 + j*16 + l15;
        #pragma unroll
        for (int r = 0; r < 4; ++r)
          buf[(mt*16 + l4*4 + r)*520 + o] = (f16)acc[mt][j][r];
      }
  }
  __syncthreads();
  f16x8 y1[12];
  #pragma unroll
  for (int mm = 0; mm < 12; ++mm)
    y1[mm] = *(const f16x8*)(&buf[(bi*12 + mm)*520 + lane*8]);

  // ---- barrier-free tail: per row, h once, wave-shfl LN, store
  const int ob0 = lane*8, ob1 = 512 + lane*8;
  const float4 ga0 = *(const float4*)(gam + (size_t)g*1024 + ob0);
  const float4 ga1 = *(const float4*)(gam + (size_t)g*1024 + ob0 + 4);
  const float4 ga2 = *(const float4*)(gam + (size_t)g*1024 + ob1);
  const float4 ga3 = *(const float4*)(gam + (size_t)g*1024 + ob1 + 4);
  const float4 be0 = *(const float4*)(bet + (size_t)g*1024 + ob0);
  const float4 be1 = *(const float4*)(bet + (size_t)g*1024 + ob0 + 4);
  const float4 be2 = *(const float4*)(bet + (size_t)g*1024 + ob1);
  const float4 be3 = *(const float4*)(bet + (size_t)g*1024 + ob1 + 4);
  const float gv[16] = {ga0.x,ga0.y,ga0.z,ga0.w, ga1.x,ga1.y,ga1.z,ga1.w,
                        ga2.x,ga2.y,ga2.z,ga2.w, ga3.x,ga3.y,ga3.z,ga3.w};
  const float bv[16] = {be0.x,be0.y,be0.z,be0.w, be1.x,be1.y,be1.z,be1.w,
                        be2.x,be2.y,be2.z,be2.w, be3.x,be3.y,be3.z,be3.w};

  #pragma unroll
  for (int i = 0; i < 6; ++i){
    const int row = w*6 + i;
    const int n = row % 12;
    const float* rl = &rel_s[bi][n*12];
    f16x8 h0 = (f16x8)(f16)0.f, h1 = (f16x8)(f16)0.f;
    #pragma unroll
    for (int mm = 0; mm < 12; ++mm){
      const f16 rv = (f16)rl[mm];
      const f16x8 rb = {rv,rv,rv,rv,rv,rv,rv,rv};
      h0 = __builtin_elementwise_fma(rb, y0[mm], h0);
      h1 = __builtin_elementwise_fma(rb, y1[mm], h1);
    }
    float hf[16];
    #pragma unroll
    for (int t = 0; t < 8; ++t){ hf[t] = (float)h0[t]; hf[8+t] = (float)h1[t]; }
    float s = 0.f, s2 = 0.f;
    #pragma unroll
    for (int t = 0; t < 16; ++t){ s += hf[t]; s2 = fmaf(hf[t], hf[t], s2); }
    #pragma unroll
    for (int d = 1; d < 64; d <<= 1){
      s  += __shfl_xor(s, d);
      s2 += __shfl_xor(s2, d);
    }
    const float mu  = s * (1.f/1024.f);
    const float var = s2 * (1.f/1024.f) - mu*mu;
    const float rs  = rsqrtf(var + 1e-5f);
    if (WS){
      f16x8 o0v, o1v;
      #pragma unroll
      for (int t = 0; t < 8; ++t){
        o0v[t] = (f16)fmaxf((hf[t]   - mu)*rs*gv[t]   + bv[t],   0.f);
        o1v[t] = (f16)fmaxf((hf[8+t] - mu)*rs*gv[8+t] + bv[8+t], 0.f);
      }
      f16* hp = hnw + ((size_t)gslot*6144 + bq*48 + row)*1024;
      *(f16x8*)(hp + ob0) = o0v;
      *(f16x8*)(hp + ob1) = o1v;
    } else {
      float* op = out1 + (size_t)(bq*48 + row)*1024;
      #pragma unroll
      for (int t = 0; t < 8; ++t){
        atomicAdd(op + ob0 + t, fmaxf((hf[t]   - mu)*rs*gv[t]   + bv[t],   0.f));
        atomicAdd(op + ob1 + t, fmaxf((hf[8+t] - mu)*rs*gv[8+t] + bv[8+t], 0.f));
      }
    }
  }
}

// ---------------------------------------------------------------- reduce over g-slots
__global__ __launch_bounds__(256) void kreduce(const f16* __restrict__ hnw,
                                               float* __restrict__ out1,
                                               int p, int first, int n8){
  int i = blockIdx.x * 256 + threadIdx.x;
  if (i >= n8) return;
  float acc[8];
  #pragma unroll
  for (int t = 0; t < 8; ++t) acc[t] = 0.f;
  for (int s = 0; s < p; ++s){
    const f16x8 v = reinterpret_cast<const f16x8*>(hnw + (size_t)s*6291456)[i];
    #pragma unroll
    for (int t = 0; t < 8; ++t) acc[t] += (float)v[t];
  }
  if (!first){
    float4 p0 = reinterpret_cast<const float4*>(out1)[i*2];
    float4 p1 = reinterpret_cast<const float4*>(out1)[i*2 + 1];
    acc[0]+=p0.x; acc[1]+=p0.y; acc[2]+=p0.z; acc[3]+=p0.w;
    acc[4]+=p1.x; acc[5]+=p1.y; acc[6]+=p1.z; acc[7]+=p1.w;
  }
  float4 o0 = {acc[0], acc[1], acc[2], acc[3]};
  float4 o1 = {acc[4], acc[5], acc[6], acc[7]};
  reinterpret_cast<float4*>(out1)[i*2]     = o0;
  reinterpret_cast<float4*>(out1)[i*2 + 1] = o1;
}

// ---------------------------------------------------------------- launcher
extern "C" void kernel_launch(void* const* d_in, const int* in_sizes, int n_in,
                              void* d_out, int out_size, void* d_ws, size_t ws_size,
                              hipStream_t stream)
{
  const float* x_f   = (const float*)d_in[0];
  const float* boxes = (const float*)d_in[1];
  const float* Wt_f  = (const float*)d_in[2];
  const float* bt_f  = (const float*)d_in[3];
  const float* Wp_f  = (const float*)d_in[4];
  const float* bp_f  = (const float*)d_in[5];
  const float* Wg_f  = (const float*)d_in[6];
  const float* gam   = (const float*)d_in[7];
  const float* bet   = (const float*)d_in[8];

  float* out1 = (float*)d_out;
  float* out2 = out1 + (size_t)512*12*1024;

  char* ws = (char*)d_ws;
  f16*  xh   = (f16*)(ws);                       // 12,582,912 B
  f16*  Wgh  = (f16*)(ws + 12582912);            // 33,554,432 B
  float* relw = (float*)(ws + 46137344);         //  4,718,592 B
  char* pool = ws + 50855936;
  f16*  Wth  = (f16*)(pool);                     //  8,388,608 B (krel only)
  f16*  Wph  = (f16*)(pool + 8388608);           //  8,388,608 B (krel only)
  f16*  hnw  = (f16*)(pool);                     // p * 12,582,912 B (post-krel)

  const size_t slot_bytes = 12582912u;
  size_t avail = (ws_size > 50855936u) ? ws_size - 50855936u : 0u;
  const bool krel_fit = avail >= 16777216u;
  int p = 16;
  while (p > 1 && (size_t)p * slot_bytes > avail) p >>= 1;
  const bool use_ws = krel_fit && (avail >= slot_bytes);

  cvt_kernel<<<6144,  256, 0, stream>>>(x_f,  xh,  6291456/4);
  cvt_kernel<<<16384, 256, 0, stream>>>(Wg_f, Wgh, 16777216/4);
  cvt_kernel<<<4096,  256, 0, stream>>>(Wt_f, Wth, 4194304/4);
  cvt_kernel<<<4096,  256, 0, stream>>>(Wp_f, Wph, 4194304/4);

  krel<<<2048, 256, 0, stream>>>(xh, Wth, Wph, bt_f, bp_f, boxes, relw, out2);

  if (use_ws){
    int first = 1;
    for (int g0 = 0; g0 < 16; g0 += p){
      kh<true><<<128*p, 512, 0, stream>>>(xh, Wgh, relw, gam, bet, out1, hnw, g0, p);
      kreduce<<<3072, 256, 0, stream>>>(hnw, out1, p, first, 786432);
      first = 0;
    }
  } else {
    hipMemsetAsync(out1, 0, (size_t)512*12*1024*sizeof(float), stream);
    kh<false><<<2048, 512, 0, stream>>>(xh, Wgh, relw, gam, bet, out1, hnw, 0, 16);
  }
}

// Round 7
// 1035.823 us; speedup vs baseline: 3.0518x; 1.0111x over previous
//
#include <hip/hip_runtime.h>
#include <hip/hip_fp16.h>

typedef _Float16 f16;
typedef _Float16 f16x8 __attribute__((ext_vector_type(8)));
typedef _Float16 f16x4 __attribute__((ext_vector_type(4)));
typedef float    f32x4 __attribute__((ext_vector_type(4)));

__device__ __forceinline__ f32x4 mfma16(f16x8 a, f16x8 b, f32x4 c){
  return __builtin_amdgcn_mfma_f32_16x16x32_f16(a, b, c, 0, 0, 0);
}
__device__ __forceinline__ int imin(int a, int b){ return a < b ? a : b; }

// async global->LDS, 16B per lane; dest = wave-uniform base + lane*16
__device__ __forceinline__ void gload_lds16(const f16* g, f16* l){
  __builtin_amdgcn_global_load_lds(
      (const __attribute__((address_space(1))) void*)g,
      (__attribute__((address_space(3))) void*)l, 16, 0, 0);
}

// ---------------------------------------------------------------- f32 -> f16
__global__ void cvt_kernel(const float* __restrict__ src, f16* __restrict__ dst, int n4){
  int i = blockIdx.x * 256 + threadIdx.x;
  if (i < n4){
    float4 v = reinterpret_cast<const float4*>(src)[i];
    f16x4 h;
    h[0] = (f16)v.x; h[1] = (f16)v.y; h[2] = (f16)v.z; h[3] = (f16)v.w;
    reinterpret_cast<f16x4*>(dst)[i] = h;
  }
}

// ---------------------------------------------------------------- rel kernel
// grid: 2048 blocks = (bq,g), 512 threads (8 waves). Full 48x1024 A staged
// once in LDS (row stride 1040); zero-barrier kk loop with ping-pong B regs.
// Wave w computes theta & phi o-cols [w*32, w*32+32).
__global__ __launch_bounds__(512, 2) void krel(
    const f16* __restrict__ xh, const f16* __restrict__ Wth, const f16* __restrict__ Wph,
    const float* __restrict__ bth, const float* __restrict__ bph,
    const float* __restrict__ boxes, float* __restrict__ relw, float* __restrict__ out2)
{
  const int bid  = blockIdx.x;
  const int slot = bid & 7, idx = bid >> 3;          // XCD swizzle: same g stays on one XCD
  const int g    = slot + ((idx >> 7) << 3);
  const int bq   = idx & 127;
  const int tid  = threadIdx.x;
  const int w    = tid >> 6, lane = tid & 63;
  const int l15  = lane & 15, l4 = lane >> 4;

  __shared__ f16 stage[48*1040];      // 99,840 B; reused as thS/phS after GEMM
  f16* thS = stage;                   // [48][264]
  f16* phS = stage + 48*264;          // [48][264]

  // ---- stage full A-tile (wave w: rows w*6..w*6+5, 2 insts/row)
  #pragma unroll
  for (int r = 0; r < 6; ++r){
    const int row = w*6 + r;
    const f16* src = xh + (size_t)(bq*48 + row)*1024 + lane*8;
    gload_lds16(src,       &stage[row*1040]);
    gload_lds16(src + 512, &stage[row*1040 + 512]);
  }
  __syncthreads();

  const f16* Tb = Wth + (size_t)(g*256 + w*32 + l15)*1024 + l4*8;
  const f16* Pb = Wph + (size_t)(g*256 + w*32 + l15)*1024 + l4*8;

  const f32x4 fz = {0.f, 0.f, 0.f, 0.f};
  f32x4 accT[3][2], accP[3][2];
  #pragma unroll
  for (int mt = 0; mt < 3; ++mt)
    #pragma unroll
    for (int j = 0; j < 2; ++j){ accT[mt][j] = fz; accP[mt][j] = fz; }

  f16x8 t0[2], p0[2], t1[2], p1[2];
  #pragma unroll
  for (int j = 0; j < 2; ++j){
    t0[j] = *(const f16x8*)(Tb + j*16384);
    p0[j] = *(const f16x8*)(Pb + j*16384);
  }

  for (int kk = 0; kk < 32; kk += 2){
    const int f1 = (kk + 1) << 5;
    #pragma unroll
    for (int j = 0; j < 2; ++j){
      t1[j] = *(const f16x8*)(Tb + j*16384 + f1);
      p1[j] = *(const f16x8*)(Pb + j*16384 + f1);
    }
    #pragma unroll
    for (int mt = 0; mt < 3; ++mt){
      const f16x8 a = *(const f16x8*)(&stage[(mt*16 + l15)*1040 + (kk << 5) + l4*8]);
      #pragma unroll
      for (int j = 0; j < 2; ++j){
        accT[mt][j] = mfma16(a, t0[j], accT[mt][j]);
        accP[mt][j] = mfma16(a, p0[j], accP[mt][j]);
      }
    }
    if (kk + 2 < 32){
      const int f2 = (kk + 2) << 5;
      #pragma unroll
      for (int j = 0; j < 2; ++j){
        t0[j] = *(const f16x8*)(Tb + j*16384 + f2);
        p0[j] = *(const f16x8*)(Pb + j*16384 + f2);
      }
    }
    #pragma unroll
    for (int mt = 0; mt < 3; ++mt){
      const f16x8 a = *(const f16x8*)(&stage[(mt*16 + l15)*1040 + f1 + l4*8]);
      #pragma unroll
      for (int j = 0; j < 2; ++j){
        accT[mt][j] = mfma16(a, t1[j], accT[mt][j]);
        accP[mt][j] = mfma16(a, p1[j], accP[mt][j]);
      }
    }
  }
  __syncthreads();   // all stage reads done; safe to overwrite with thS/phS

  #pragma unroll
  for (int j = 0; j < 2; ++j){
    const int ko = w*32 + j*16 + l15;
    const float bT = bth[g*256 + ko];
    const float bP = bph[g*256 + ko];
    #pragma unroll
    for (int mt = 0; mt < 3; ++mt)
      #pragma unroll
      for (int r = 0; r < 4; ++r){
        const int row = mt*16 + l4*4 + r;
        thS[row*264 + ko] = (f16)(accT[mt][j][r] + bT);
        phS[row*264 + ko] = (f16)(accP[mt][j][r] + bP);
      }
  }
  __syncthreads();

  if (w < 4){
    const int bi = w;
    const int bglob = bq*4 + bi;
    f32x4 sa = fz;
    const int arow = imin(bi*12 + l15, 47);
    #pragma unroll
    for (int k8 = 0; k8 < 8; ++k8){
      const f16x8 a = *(const f16x8*)(&thS[arow*264 + k8*32 + l4*8]);
      const f16x8 b = *(const f16x8*)(&phS[arow*264 + k8*32 + l4*8]);
      sa = mfma16(a, b, sa);
    }
    const int m  = l15;
    const int mc = imin(m, 11);
    const float4 bxm = *(const float4*)(boxes + (size_t)(bglob*12 + mc)*4);
    const float cxm = (bxm.x + bxm.z)*0.5f, cym = (bxm.y + bxm.w)*0.5f;
    const float sqm = cxm*cxm + cym*cym;
    #pragma unroll
    for (int r = 0; r < 4; ++r){
      const int n  = l4*4 + r;
      const int nc = imin(n, 11);
      const float4 bxn = *(const float4*)(boxes + (size_t)(bglob*12 + nc)*4);
      const float cxn = (bxn.x + bxn.z)*0.5f, cyn = (bxn.y + bxn.w)*0.5f;
      const float sqn = cxn*cxn + cyn*cyn;
      const float dot = cxn*cxm + cyn*cym;
      const float d2  = (sqn - 2.f*dot) + sqm;
      const float dist = sqrtf(fmaxf(d2, 0.f));
      float val = sa[r] * 0.0625f;
      if (dist > 0.2f || m >= 12) val = -__builtin_inff();
      float mx = val;
      #pragma unroll
      for (int d = 1; d < 16; d <<= 1) mx = fmaxf(mx, __shfl_xor(mx, d));
      const float e = expf(val - mx);
      float s = e;
      #pragma unroll
      for (int d = 1; d < 16; d <<= 1) s += __shfl_xor(s, d);
      const float rv = e / s;
      if (n < 12 && m < 12){
        relw[((size_t)(bglob*16 + g))*144 + n*12 + m] = rv;
        if (g == 15) out2[(size_t)bglob*144 + n*12 + m] = rv;
      }
    }
  }
}

// ---------------------------------------------------------------- h kernel
// grid = 128*p blocks, 512 threads (8 waves). Full A-tile staged once;
// zero-barrier kk loop with ping-pong B regs; register-resident epilogue.
template<bool WS>
__global__ __launch_bounds__(512, 2) void kh(
    const f16* __restrict__ xh, const f16* __restrict__ Wgh,
    const float* __restrict__ relw, const float* __restrict__ gam,
    const float* __restrict__ bet, float* __restrict__ out1, f16* __restrict__ hnw,
    int g0, int p)
{
  const int bid = blockIdx.x;
  int g, bq, gslot;
  if (p == 16){
    const int slot = bid & 7, idx = bid >> 3;        // XCD swizzle
    g = slot + ((idx >> 7) << 3);
    bq = idx & 127;
    gslot = g;
  } else {
    const int r = bid & 7, q = bid >> 3;
    const int lp = (p == 8) ? 3 : (p == 4) ? 2 : (p == 2) ? 1 : 0;
    gslot = r & (p - 1);
    g = g0 + gslot;
    bq = q * (8 >> lp) + (r >> lp);
  }
  const int tid  = threadIdx.x;
  const int w    = tid >> 6, lane = tid & 63;
  const int l15  = lane & 15, l4 = lane >> 4;

  __shared__ f16   stage[48*1040];   // 99,840 B; reused as ylds [48][520]
  __shared__ float rel_s[4][144];
  f16* ylds = stage;

  // ---- stage full A-tile + rel
  #pragma unroll
  for (int r = 0; r < 6; ++r){
    const int row = w*6 + r;
    const f16* src = xh + (size_t)(bq*48 + row)*1024 + lane*8;
    gload_lds16(src,       &stage[row*1040]);
    gload_lds16(src + 512, &stage[row*1040 + 512]);
  }
  for (int t = tid; t < 576; t += 512){
    int bi = t / 144, nm = t % 144;
    rel_s[bi][nm] = relw[((size_t)((bq*4 + bi)*16 + g))*144 + nm];
  }
  __syncthreads();

  const f16* Bb = Wgh + (size_t)(g*1024 + w*128 + l15)*1024 + l4*8;

  const f32x4 fz = {0.f, 0.f, 0.f, 0.f};
  f32x4 acc[3][8];
  #pragma unroll
  for (int mt = 0; mt < 3; ++mt)
    #pragma unroll
    for (int j = 0; j < 8; ++j) acc[mt][j] = fz;

  f16x8 b0[8], b1[8];
  #pragma unroll
  for (int j = 0; j < 8; ++j) b0[j] = *(const f16x8*)(Bb + j*16384);

  for (int kk = 0; kk < 32; kk += 2){
    const int f1 = (kk + 1) << 5;
    #pragma unroll
    for (int j = 0; j < 8; ++j) b1[j] = *(const f16x8*)(Bb + j*16384 + f1);
    #pragma unroll
    for (int mt = 0; mt < 3; ++mt){
      const f16x8 a = *(const f16x8*)(&stage[(mt*16 + l15)*1040 + (kk << 5) + l4*8]);
      #pragma unroll
      for (int j = 0; j < 8; ++j) acc[mt][j] = mfma16(a, b0[j], acc[mt][j]);
    }
    if (kk + 2 < 32){
      const int f2 = (kk + 2) << 5;
      #pragma unroll
      for (int j = 0; j < 8; ++j) b0[j] = *(const f16x8*)(Bb + j*16384 + f2);
    }
    #pragma unroll
    for (int mt = 0; mt < 3; ++mt){
      const f16x8 a = *(const f16x8*)(&stage[(mt*16 + l15)*1040 + f1 + l4*8]);
      #pragma unroll
      for (int j = 0; j < 8; ++j) acc[mt][j] = mfma16(a, b1[j], acc[mt][j]);
    }
  }
  __syncthreads();   // stage reads done; stage becomes ylds

  const int bi = w >> 1;             // batch handled by this wave

  // ---- y half0 (cols 0..511) written by waves 0-3; cache to regs
  if (w < 4){
    #pragma unroll
    for (int mt = 0; mt < 3; ++mt)
      #pragma unroll
      for (int j = 0; j < 8; ++j){
        const int o = w*128 + j*16 + l15;
        #pragma unroll
        for (int r = 0; r < 4; ++r)
          ylds[(mt*16 + l4*4 + r)*520 + o] = (f16)acc[mt][j][r];
      }
  }
  __syncthreads();
  f16x8 y0[12];
  #pragma unroll
  for (int mm = 0; mm < 12; ++mm)
    y0[mm] = *(const f16x8*)(&ylds[(bi*12 + mm)*520 + lane*8]);
  __syncthreads();

  // ---- y half1 (cols 512..1023) written by waves 4-7; cache to regs
  if (w >= 4){
    #pragma unroll
    for (int mt = 0; mt < 3; ++mt)
      #pragma unroll
      for (int j = 0; j < 8; ++j){
        const int o = (w - 4)*128 + j*16 + l15;
        #pragma unroll
        for (int r = 0; r < 4; ++r)
          ylds[(mt*16 + l4*4 + r)*520 + o] = (f16)acc[mt][j][r];
      }
  }
  __syncthreads();
  f16x8 y1[12];
  #pragma unroll
  for (int mm = 0; mm < 12; ++mm)
    y1[mm] = *(const f16x8*)(&ylds[(bi*12 + mm)*520 + lane*8]);

  // ---- barrier-free tail: per row, h once, wave-shfl LN, store
  const int ob0 = lane*8, ob1 = 512 + lane*8;
  const float4 ga0 = *(const float4*)(gam + (size_t)g*1024 + ob0);
  const float4 ga1 = *(const float4*)(gam + (size_t)g*1024 + ob0 + 4);
  const float4 ga2 = *(const float4*)(gam + (size_t)g*1024 + ob1);
  const float4 ga3 = *(const float4*)(gam + (size_t)g*1024 + ob1 + 4);
  const float4 be0 = *(const float4*)(bet + (size_t)g*1024 + ob0);
  const float4 be1 = *(const float4*)(bet + (size_t)g*1024 + ob0 + 4);
  const float4 be2 = *(const float4*)(bet + (size_t)g*1024 + ob1);
  const float4 be3 = *(const float4*)(bet + (size_t)g*1024 + ob1 + 4);
  const float gv[16] = {ga0.x,ga0.y,ga0.z,ga0.w, ga1.x,ga1.y,ga1.z,ga1.w,
                        ga2.x,ga2.y,ga2.z,ga2.w, ga3.x,ga3.y,ga3.z,ga3.w};
  const float bv[16] = {be0.x,be0.y,be0.z,be0.w, be1.x,be1.y,be1.z,be1.w,
                        be2.x,be2.y,be2.z,be2.w, be3.x,be3.y,be3.z,be3.w};

  #pragma unroll
  for (int i = 0; i < 6; ++i){
    const int row = w*6 + i;
    const int n = row % 12;
    const float* rl = &rel_s[bi][n*12];
    f16x8 h0 = (f16x8)(f16)0.f, h1 = (f16x8)(f16)0.f;
    #pragma unroll
    for (int mm = 0; mm < 12; ++mm){
      const f16 rv = (f16)rl[mm];
      const f16x8 rb = {rv,rv,rv,rv,rv,rv,rv,rv};
      h0 = __builtin_elementwise_fma(rb, y0[mm], h0);
      h1 = __builtin_elementwise_fma(rb, y1[mm], h1);
    }
    float hf[16];
    #pragma unroll
    for (int t = 0; t < 8; ++t){ hf[t] = (float)h0[t]; hf[8+t] = (float)h1[t]; }
    float s = 0.f, s2 = 0.f;
    #pragma unroll
    for (int t = 0; t < 16; ++t){ s += hf[t]; s2 = fmaf(hf[t], hf[t], s2); }
    #pragma unroll
    for (int d = 1; d < 64; d <<= 1){
      s  += __shfl_xor(s, d);
      s2 += __shfl_xor(s2, d);
    }
    const float mu  = s * (1.f/1024.f);
    const float var = s2 * (1.f/1024.f) - mu*mu;
    const float rs  = rsqrtf(var + 1e-5f);
    if (WS){
      f16x8 o0v, o1v;
      #pragma unroll
      for (int t = 0; t < 8; ++t){
        o0v[t] = (f16)fmaxf((hf[t]   - mu)*rs*gv[t]   + bv[t],   0.f);
        o1v[t] = (f16)fmaxf((hf[8+t] - mu)*rs*gv[8+t] + bv[8+t], 0.f);
      }
      f16* hp = hnw + ((size_t)gslot*6144 + bq*48 + row)*1024;
      *(f16x8*)(hp + ob0) = o0v;
      *(f16x8*)(hp + ob1) = o1v;
    } else {
      float* op = out1 + (size_t)(bq*48 + row)*1024;
      #pragma unroll
      for (int t = 0; t < 8; ++t){
        atomicAdd(op + ob0 + t, fmaxf((hf[t]   - mu)*rs*gv[t]   + bv[t],   0.f));
        atomicAdd(op + ob1 + t, fmaxf((hf[8+t] - mu)*rs*gv[8+t] + bv[8+t], 0.f));
      }
    }
  }
}

// ---------------------------------------------------------------- reduce over g-slots
__global__ __launch_bounds__(256) void kreduce(const f16* __restrict__ hnw,
                                               float* __restrict__ out1,
                                               int p, int first, int n8){
  int i = blockIdx.x * 256 + threadIdx.x;
  if (i >= n8) return;
  float acc[8];
  #pragma unroll
  for (int t = 0; t < 8; ++t) acc[t] = 0.f;
  for (int s = 0; s < p; ++s){
    const f16x8 v = reinterpret_cast<const f16x8*>(hnw + (size_t)s*6291456)[i];
    #pragma unroll
    for (int t = 0; t < 8; ++t) acc[t] += (float)v[t];
  }
  if (!first){
    float4 p0 = reinterpret_cast<const float4*>(out1)[i*2];
    float4 p1 = reinterpret_cast<const float4*>(out1)[i*2 + 1];
    acc[0]+=p0.x; acc[1]+=p0.y; acc[2]+=p0.z; acc[3]+=p0.w;
    acc[4]+=p1.x; acc[5]+=p1.y; acc[6]+=p1.z; acc[7]+=p1.w;
  }
  float4 o0 = {acc[0], acc[1], acc[2], acc[3]};
  float4 o1 = {acc[4], acc[5], acc[6], acc[7]};
  reinterpret_cast<float4*>(out1)[i*2]     = o0;
  reinterpret_cast<float4*>(out1)[i*2 + 1] = o1;
}

// ---------------------------------------------------------------- launcher
extern "C" void kernel_launch(void* const* d_in, const int* in_sizes, int n_in,
                              void* d_out, int out_size, void* d_ws, size_t ws_size,
                              hipStream_t stream)
{
  const float* x_f   = (const float*)d_in[0];
  const float* boxes = (const float*)d_in[1];
  const float* Wt_f  = (const float*)d_in[2];
  const float* bt_f  = (const float*)d_in[3];
  const float* Wp_f  = (const float*)d_in[4];
  const float* bp_f  = (const float*)d_in[5];
  const float* Wg_f  = (const float*)d_in[6];
  const float* gam   = (const float*)d_in[7];
  const float* bet   = (const float*)d_in[8];

  float* out1 = (float*)d_out;
  float* out2 = out1 + (size_t)512*12*1024;

  char* ws = (char*)d_ws;
  f16*  xh   = (f16*)(ws);                       // 12,582,912 B
  f16*  Wgh  = (f16*)(ws + 12582912);            // 33,554,432 B
  float* relw = (float*)(ws + 46137344);         //  4,718,592 B
  char* pool = ws + 50855936;
  f16*  Wth  = (f16*)(pool);                     //  8,388,608 B (krel only)
  f16*  Wph  = (f16*)(pool + 8388608);           //  8,388,608 B (krel only)
  f16*  hnw  = (f16*)(pool);                     // p * 12,582,912 B (post-krel)

  const size_t slot_bytes = 12582912u;
  size_t avail = (ws_size > 50855936u) ? ws_size - 50855936u : 0u;
  const bool krel_fit = avail >= 16777216u;
  int p = 16;
  while (p > 1 && (size_t)p * slot_bytes > avail) p >>= 1;
  const bool use_ws = krel_fit && (avail >= slot_bytes);

  cvt_kernel<<<6144,  256, 0, stream>>>(x_f,  xh,  6291456/4);
  cvt_kernel<<<16384, 256, 0, stream>>>(Wg_f, Wgh, 16777216/4);
  cvt_kernel<<<4096,  256, 0, stream>>>(Wt_f, Wth, 4194304/4);
  cvt_kernel<<<4096,  256, 0, stream>>>(Wp_f, Wph, 4194304/4);

  krel<<<2048, 512, 0, stream>>>(xh, Wth, Wph, bt_f, bp_f, boxes, relw, out2);

  if (use_ws){
    int first = 1;
    for (int g0 = 0; g0 < 16; g0 += p){
      kh<true><<<128*p, 512, 0, stream>>>(xh, Wgh, relw, gam, bet, out1, hnw, g0, p);
      kreduce<<<3072, 256, 0, stream>>>(hnw, out1, p, first, 786432);
      first = 0;
    }
  } else {
    hipMemsetAsync(out1, 0, (size_t)512*12*1024*sizeof(float), stream);
    kh<false><<<2048, 512, 0, stream>>>(xh, Wgh, relw, gam, bet, out1, hnw, 0, 16);
  }
}